// Round 1
// baseline (1398.137 us; speedup 1.0000x reference)
//
#include <hip/hip_runtime.h>
#include <stdint.h>
#include <stddef.h>

typedef short bf16x8 __attribute__((ext_vector_type(8)));
typedef unsigned short ushort8 __attribute__((ext_vector_type(8)));
typedef float f32x4 __attribute__((ext_vector_type(4)));

__device__ __forceinline__ unsigned short f2bf(float f) {
  union { float f; unsigned int u; } v; v.f = f;
  unsigned int r = v.u + 0x7FFFu + ((v.u >> 16) & 1u);  // round-to-nearest-even
  return (unsigned short)(r >> 16);
}

// ---------------- weight prep ----------------
// Build padded bf16 W_cat [512][2016] from W_sh(400x1000), W_hu(400x500), W_mo(400x500)
__global__ void build_wc(const float* __restrict__ Wsh, const float* __restrict__ Whu,
                         const float* __restrict__ Wmo, unsigned short* __restrict__ Bp)
{
  int i = blockIdx.x * 256 + threadIdx.x;
  const int KP = 2016;
  if (i >= 512 * KP) return;
  int n = i / KP, k = i - n * KP;
  float v = 0.f;
  if (n < 400) {
    if (k < 1000)      v = Wsh[n * 1000 + k];
    else if (k < 1500) v = Whu[n * 500 + (k - 1000)];
    else if (k < 2000) v = Wmo[n * 500 + (k - 1500)];
  }
  Bp[i] = f2bf(v);
}

// Generic pad+convert: W [N][K] f32 -> Bp [Ntot][Kpad] bf16 (zero padded)
__global__ void pad_w(const float* __restrict__ W, unsigned short* __restrict__ Bp,
                      int N, int K, int Kpad, int Ntot)
{
  int i = blockIdx.x * 256 + threadIdx.x;
  if (i >= Ntot * Kpad) return;
  int n = i / Kpad, k = i - n * Kpad;
  float v = (n < N && k < K) ? W[n * K + k] : 0.f;
  Bp[i] = f2bf(v);
}

__global__ void comb_bias(const float* a, const float* b, const float* c, float* o, int n) {
  int i = blockIdx.x * blockDim.x + threadIdx.x;
  if (i < n) o[i] = a[i] + b[i] + c[i];
}

// ---------------- MFMA GEMM: C[M][N] = A[M][K](f32->bf16) @ Bp[n][k]^T + bias ----------------
// Bp is padded bf16 [Ntot][Kpad], Ntot = nchunks*128, Kpad % 32 == 0.
// 256 threads = 4 waves (2x2), wave tile 64x64, block tile 128x128, BK=32.
__global__ __launch_bounds__(256) void gemm_bf16(
    const float* __restrict__ A, const unsigned short* __restrict__ Bp,
    const float* __restrict__ bias, float* __restrict__ C,
    int M, int N, int K, int Kpad, int nchunks)
{
  __shared__ unsigned short As[2][128][32];
  __shared__ unsigned short Bs[2][128][32];
  const int tid = threadIdx.x;
  const int lane = tid & 63;
  const int wr = (tid >> 6) >> 1;
  const int wc = (tid >> 6) & 1;
  const int rowBase = blockIdx.x * 128;
  const int ksteps = Kpad >> 5;
  const int sRow = tid >> 1;           // 0..127
  const int sK = (tid & 1) << 4;       // 0 or 16
  const int arow = rowBase + sRow;
  const bool arowOK = (arow < M);
  const float* aBase = A + (size_t)arow * K + sK;
  const int fRow = lane & 15;
  const int fK = (lane >> 4) << 3;     // 0,8,16,24

  for (int chunk = 0; chunk < nchunks; ++chunk) {
    const int colBase = chunk << 7;
    const unsigned short* bBase = Bp + (size_t)(colBase + sRow) * Kpad + sK;
    f32x4 acc[4][4] = {};
    float aReg[16];
    ushort8 bReg0, bReg1;

    auto loadTile = [&](int T) {
      const int k0 = T << 5;
      #pragma unroll
      for (int j = 0; j < 4; ++j) {
        const int kk = k0 + sK + (j << 2);
        if (arowOK && kk < K) {           // K % 4 == 0 for all our GEMMs
          f32x4 v = *(const f32x4*)(aBase + k0 + (j << 2));
          aReg[j*4+0] = v[0]; aReg[j*4+1] = v[1]; aReg[j*4+2] = v[2]; aReg[j*4+3] = v[3];
        } else {
          aReg[j*4+0] = 0.f; aReg[j*4+1] = 0.f; aReg[j*4+2] = 0.f; aReg[j*4+3] = 0.f;
        }
      }
      bReg0 = *(const ushort8*)(bBase + k0);      // Bp fully padded: no guards
      bReg1 = *(const ushort8*)(bBase + k0 + 8);
    };
    auto writeTile = [&](int buf) {
      ushort8 t0, t1;
      #pragma unroll
      for (int j = 0; j < 8; ++j) { t0[j] = f2bf(aReg[j]); t1[j] = f2bf(aReg[8 + j]); }
      *(ushort8*)&As[buf][sRow][sK]     = t0;
      *(ushort8*)&As[buf][sRow][sK + 8] = t1;
      *(ushort8*)&Bs[buf][sRow][sK]     = bReg0;
      *(ushort8*)&Bs[buf][sRow][sK + 8] = bReg1;
    };
    auto compute = [&](int buf) {
      bf16x8 af[4], bfr[4];
      #pragma unroll
      for (int mi = 0; mi < 4; ++mi)
        af[mi] = *(const bf16x8*)&As[buf][(wr << 6) + (mi << 4) + fRow][fK];
      #pragma unroll
      for (int ni = 0; ni < 4; ++ni)
        bfr[ni] = *(const bf16x8*)&Bs[buf][(wc << 6) + (ni << 4) + fRow][fK];
      #pragma unroll
      for (int mi = 0; mi < 4; ++mi)
        #pragma unroll
        for (int ni = 0; ni < 4; ++ni)
          acc[mi][ni] = __builtin_amdgcn_mfma_f32_16x16x32_bf16(af[mi], bfr[ni], acc[mi][ni], 0, 0, 0);
    };

    loadTile(0);
    writeTile(0);
    __syncthreads();
    for (int t = 0; t < ksteps; ++t) {
      const int cur = t & 1;
      if (t + 1 < ksteps) loadTile(t + 1);
      compute(cur);
      if (t + 1 < ksteps) {
        __syncthreads();
        writeTile(cur ^ 1);
        __syncthreads();
      }
    }
    // epilogue: C/D layout col=lane&15, row=(lane>>4)*4+r  [m89-verified]
    #pragma unroll
    for (int mi = 0; mi < 4; ++mi) {
      const int row0 = rowBase + (wr << 6) + (mi << 4) + ((lane >> 4) << 2);
      #pragma unroll
      for (int ni = 0; ni < 4; ++ni) {
        const int col = colBase + (wc << 6) + (ni << 4) + fRow;
        if (col < N) {
          const float bv = bias[col];
          #pragma unroll
          for (int r = 0; r < 4; ++r) {
            const int row = row0 + r;
            if (row < M) C[(size_t)row * N + col] = acc[mi][ni][r] + bv;
          }
        }
      }
    }
    __syncthreads();   // protect LDS before next chunk restages
  }
}

// ---------------- CSR build ----------------
__global__ void count_deg(const int* __restrict__ dst, int* __restrict__ cnt, int E) {
  int e = blockIdx.x * 256 + threadIdx.x;
  if (e < E) atomicAdd(&cnt[dst[e]], 1);
}

// single-block scan, 1024 threads x 8 elems per chunk
__global__ void scan_indptr(const int* __restrict__ cnt, int* __restrict__ indptr, int n) {
  __shared__ int sh[1024];
  __shared__ int carrySh;
  const int t = threadIdx.x;
  if (t == 0) carrySh = 0;
  __syncthreads();
  for (int base = 0; base < n; base += 8192) {
    int v[8]; int tsum = 0;
    #pragma unroll
    for (int i = 0; i < 8; ++i) {
      int idx = base + t * 8 + i;
      v[i] = (idx < n) ? cnt[idx] : 0;
      tsum += v[i];
    }
    sh[t] = tsum; __syncthreads();
    for (int off = 1; off < 1024; off <<= 1) {
      int add = (t >= off) ? sh[t - off] : 0;
      __syncthreads();
      sh[t] += add;
      __syncthreads();
    }
    int excl = carrySh + sh[t] - tsum;
    #pragma unroll
    for (int i = 0; i < 8; ++i) {
      int idx = base + t * 8 + i;
      if (idx < n) indptr[idx] = excl;
      excl += v[i];
    }
    __syncthreads();
    if (t == 1023) carrySh += sh[1023];
    __syncthreads();
  }
  if (t == 0) indptr[n] = carrySh;
}

__global__ void fill_csr(const int* __restrict__ src, const int* __restrict__ dst,
                         const int* __restrict__ eid, const float* __restrict__ wall,
                         const int* __restrict__ indptr, int* __restrict__ fillc,
                         int* __restrict__ esrc, float* __restrict__ ew, int E)
{
  int e = blockIdx.x * 256 + threadIdx.x;
  if (e >= E) return;
  int d = dst[e];
  int pos = atomicAdd(&fillc[d], 1);
  int slot = indptr[d] + pos;
  esrc[slot] = src[e];
  ew[slot] = wall[eid[e]];
}

// ---------------- segment mean-aggregate: one wave per dst node, 400 dims ----------------
__global__ __launch_bounds__(256) void seg_mean(
    const float* __restrict__ hsrc, const int* __restrict__ indptr,
    const int* __restrict__ esrc, const float* __restrict__ ew,
    float* __restrict__ out, int nDst)
{
  const int node = blockIdx.x * 4 + (threadIdx.x >> 6);
  if (node >= nDst) return;
  const int lane = threadIdx.x & 63;
  float acc[7];
  const float* hp = hsrc + (size_t)node * 400;
  #pragma unroll
  for (int j = 0; j < 7; ++j) {
    int d2 = lane + j * 64;
    acc[j] = (d2 < 400) ? hp[d2] : 0.f;   // init with h_dst
  }
  const int e0 = indptr[node], e1 = indptr[node + 1];
  for (int e = e0; e < e1; ++e) {
    const int s = esrc[e];
    const float w = ew[e];
    const float* sp = hsrc + (size_t)s * 400;
    #pragma unroll
    for (int j = 0; j < 7; ++j) {
      int d2 = lane + j * 64;
      if (d2 < 400) acc[j] += sp[d2] * w;
    }
  }
  const float inv = 1.f / ((float)(e1 - e0) + 1.f);
  float* op = out + (size_t)node * 400;
  #pragma unroll
  for (int j = 0; j < 7; ++j) {
    int d2 = lane + j * 64;
    if (d2 < 400) op[d2] = acc[j] * inv;
  }
}

// ---------------- batchnorm stats + finalize + domain head ----------------
__global__ void bn_stats(const float* __restrict__ d, float* __restrict__ stats, int rows) {
  int lane = threadIdx.x & 63;
  int wid = (blockIdx.x * blockDim.x + threadIdx.x) >> 6;
  int nw = (gridDim.x * blockDim.x) >> 6;
  if (lane >= 50) return;
  float s = 0.f, s2 = 0.f;
  for (int r = wid; r < rows; r += nw) {
    float v = d[r * 50 + lane];
    s += v; s2 += v * v;
  }
  atomicAdd(&stats[lane], s);
  atomicAdd(&stats[50 + lane], s2);
}

__global__ void bn_final(const float* __restrict__ stats, const float* __restrict__ gamma,
                         const float* __restrict__ beta, float* __restrict__ ss, int rows) {
  int c = threadIdx.x;
  if (c >= 50) return;
  float mu = stats[c] / rows;
  float var = stats[50 + c] / rows - mu * mu;
  float inv = rsqrtf(var + 1e-5f);
  float sc = gamma[c] * inv;
  ss[c] = sc;
  ss[50 + c] = beta[c] - mu * sc;
}

__global__ void domain_head(const float* __restrict__ d, const float* __restrict__ ss,
                            const float* __restrict__ Wd2, const float* __restrict__ bd2,
                            float* __restrict__ out, int rows) {
  int r = blockIdx.x * 256 + threadIdx.x;
  if (r >= rows) return;
  float o0 = bd2[0], o1 = bd2[1];
  const float* dr = d + (size_t)r * 50;
  #pragma unroll 10
  for (int c = 0; c < 50; ++c) {
    float v = dr[c] * ss[c] + ss[50 + c];
    v = fmaxf(v, 0.f);
    o0 += v * Wd2[c];
    o1 += v * Wd2[50 + c];
  }
  out[r * 2]     = o0;
  out[r * 2 + 1] = o1;
}

// ---------------- launch ----------------
extern "C" void kernel_launch(void* const* d_in, const int* in_sizes, int n_in,
                              void* d_out, int out_size, void* d_ws, size_t ws_size,
                              hipStream_t stream)
{
  const float* x    = (const float*)d_in[0];
  const float* wall = (const float*)d_in[1];
  const float* Wsh  = (const float*)d_in[2];
  const float* bsh  = (const float*)d_in[3];
  const float* Whu  = (const float*)d_in[4];
  const float* bhu  = (const float*)d_in[5];
  const float* Wmo  = (const float*)d_in[6];
  const float* bmo  = (const float*)d_in[7];
  const float* Wn1  = (const float*)d_in[8];
  const float* bn1  = (const float*)d_in[9];
  const float* Wn2  = (const float*)d_in[10];
  const float* bn2  = (const float*)d_in[11];
  const float* Wlin = (const float*)d_in[12];
  const float* blin = (const float*)d_in[13];
  const float* Wd1  = (const float*)d_in[14];
  const float* bd1  = (const float*)d_in[15];
  const float* gamma= (const float*)d_in[16];
  const float* beta = (const float*)d_in[17];
  const float* Wd2  = (const float*)d_in[18];
  const float* bd2  = (const float*)d_in[19];
  const int* src1 = (const int*)d_in[20];
  const int* dst1 = (const int*)d_in[21];
  const int* eid1 = (const int*)d_in[22];
  const int* src2 = (const int*)d_in[23];
  const int* dst2 = (const int*)d_in[24];
  const int* eid2 = (const int*)d_in[25];

  char* ws = (char*)d_ws;
  // big regions (lifetime-overlapped): bufA = h(96MB) -> h1(48MB) -> h2(24MB)
  //                                     bufB = hn1(48MB) -> hn2(24MB) -> d_raw(3MB)
  float* bufA = (float*)(ws);
  float* bufB = (float*)(ws + 96000000ULL);
  char* tp = ws + 144000000ULL;
  unsigned short* WCp  = (unsigned short*)(tp);
  unsigned short* WN1p = (unsigned short*)(tp + 2064384);
  unsigned short* WN2p = (unsigned short*)(tp + 2490368);
  unsigned short* WLp  = (unsigned short*)(tp + 2916352);
  unsigned short* WD1p = (unsigned short*)(tp + 3022848);
  float* b3      = (float*)(tp + 3129344);
  int*   indptr1 = (int*)(tp + 3131392);
  int*   cnt1    = (int*)(tp + 3251712);
  int*   fill1   = (int*)(tp + 3372032);
  int*   esrc1   = (int*)(tp + 3492352);
  float* ew1     = (float*)(tp + 7332352);
  int*   indptr2 = (int*)(tp + 11172352);
  int*   cnt2    = (int*)(tp + 11232768);
  int*   fill2   = (int*)(tp + 11293184);
  int*   esrc2   = (int*)(tp + 11353600);
  float* ew2     = (float*)(tp + 13273600);
  float* stats   = (float*)(tp + 15193600);
  float* ssb     = (float*)(tp + 15194112);

  const int E1 = 960000, E2 = 480000;
  const int N0 = 60000, N1 = 30000, N2 = 15000;

  // weight prep
  build_wc<<<(512 * 2016 + 255) / 256, 256, 0, stream>>>(Wsh, Whu, Wmo, WCp);
  pad_w<<<(512 * 416 + 255) / 256, 256, 0, stream>>>(Wn1, WN1p, 400, 400, 416, 512);
  pad_w<<<(512 * 416 + 255) / 256, 256, 0, stream>>>(Wn2, WN2p, 400, 400, 416, 512);
  pad_w<<<(128 * 416 + 255) / 256, 256, 0, stream>>>(Wlin, WLp, 20, 400, 416, 128);
  pad_w<<<(128 * 416 + 255) / 256, 256, 0, stream>>>(Wd1, WD1p, 50, 400, 416, 128);
  comb_bias<<<2, 256, 0, stream>>>(bsh, bhu, bmo, b3, 400);

  // zero accumulators (ws is poisoned 0xAA, and these accumulate every call)
  hipMemsetAsync(cnt1, 0, 120000, stream);
  hipMemsetAsync(fill1, 0, 120000, stream);
  hipMemsetAsync(cnt2, 0, 60000, stream);
  hipMemsetAsync(fill2, 0, 60000, stream);
  hipMemsetAsync(stats, 0, 400, stream);

  // stage 1: h = x @ Wcat.T + b3   (60000 x 400)
  gemm_bf16<<<469, 256, 0, stream>>>(x, WCp, b3, bufA, N0, 400, 2000, 2016, 4);

  // GNN layer 1
  count_deg<<<(E1 + 255) / 256, 256, 0, stream>>>(dst1, cnt1, E1);
  scan_indptr<<<1, 1024, 0, stream>>>(cnt1, indptr1, N1);
  fill_csr<<<(E1 + 255) / 256, 256, 0, stream>>>(src1, dst1, eid1, wall, indptr1, fill1, esrc1, ew1, E1);
  seg_mean<<<N1 / 4, 256, 0, stream>>>(bufA, indptr1, esrc1, ew1, bufB, N1);
  gemm_bf16<<<235, 256, 0, stream>>>(bufB, WN1p, bn1, bufA, N1, 400, 400, 416, 4);  // h1

  // GNN layer 2
  count_deg<<<(E2 + 255) / 256, 256, 0, stream>>>(dst2, cnt2, E2);
  scan_indptr<<<1, 1024, 0, stream>>>(cnt2, indptr2, N2);
  fill_csr<<<(E2 + 255) / 256, 256, 0, stream>>>(src2, dst2, eid2, wall, indptr2, fill2, esrc2, ew2, E2);
  seg_mean<<<N2 / 4, 256, 0, stream>>>(bufA, indptr2, esrc2, ew2, bufB, N2);
  gemm_bf16<<<118, 256, 0, stream>>>(bufB, WN2p, bn2, bufA, N2, 400, 400, 416, 4);  // h2

  // heads
  float* out_hx  = (float*)d_out;            // 15000 x 20
  float* out_dom = (float*)d_out + 300000;   // 15000 x 2
  gemm_bf16<<<118, 256, 0, stream>>>(bufA, WLp, blin, out_hx, N2, 20, 400, 416, 1);
  gemm_bf16<<<118, 256, 0, stream>>>(bufA, WD1p, bd1, bufB, N2, 50, 400, 416, 1);   // d_raw

  bn_stats<<<128, 256, 0, stream>>>(bufB, stats, N2);
  bn_final<<<1, 64, 0, stream>>>(stats, gamma, beta, ssb, N2);
  domain_head<<<(N2 + 255) / 256, 256, 0, stream>>>(bufB, ssb, Wd2, bd2, out_dom, N2);
}

// Round 2
// 829.876 us; speedup vs baseline: 1.6848x; 1.6848x over previous
//
#include <hip/hip_runtime.h>
#include <stdint.h>
#include <stddef.h>

typedef short bf16x8 __attribute__((ext_vector_type(8)));
typedef unsigned short ushort8 __attribute__((ext_vector_type(8)));
typedef float f32x4 __attribute__((ext_vector_type(4)));

__device__ __forceinline__ unsigned short f2bf(float f) {
  union { float f; unsigned int u; } v; v.f = f;
  unsigned int r = v.u + 0x7FFFu + ((v.u >> 16) & 1u);  // RNE
  return (unsigned short)(r >> 16);
}
__device__ __forceinline__ float bf2f(unsigned short u) {
  union { unsigned int u; float f; } v; v.u = ((unsigned int)u) << 16; return v.f;
}

// ---------------- B fragment-order builder ----------------
// Layout: for K-step t, wave-col wc(0..3), frag ni(0..7), lane(0..63), elem e(0..7):
//   idx = ((t*32 + (wc*8+ni))*64 + lane)*8 + e   [16384 ushorts per K-step]
//   col = wc*128 + ni*16 + (lane&15);  k = t*32 + (lane>>4)*8 + e
// mode 0: cat-K  (W0 400x1000, W1 400x500, W2 400x500), N=400, K=2000
// mode 1: single W0 [N x Kr]
// mode 2: head   (W0=Wlin 20x400, W1=Wd1 50x400)
__global__ void build_bfrag(const float* __restrict__ W0, const float* __restrict__ W1,
                            const float* __restrict__ W2, unsigned short* __restrict__ out,
                            int ksteps, int mode, int N, int Kr)
{
  int idx = blockIdx.x * 256 + threadIdx.x;
  int total = ksteps * 16384;
  if (idx >= total) return;
  int t = idx >> 14;
  int rem = idx & 16383;
  int e = rem & 7;
  int chunk = rem >> 3;
  int lane = chunk & 63;
  int ni = (chunk >> 6) & 7;
  int wc = chunk >> 9;
  int col = wc * 128 + ni * 16 + (lane & 15);
  int k = t * 32 + ((lane >> 4) << 3) + e;
  float v = 0.f;
  if (mode == 0) {
    if (col < 400 && k < 2000) {
      if (k < 1000)      v = W0[col * 1000 + k];
      else if (k < 1500) v = W1[col * 500 + (k - 1000)];
      else               v = W2[col * 500 + (k - 1500)];
    }
  } else if (mode == 1) {
    if (col < N && k < Kr) v = W0[col * Kr + k];
  } else {
    if (k < 400) {
      if (col < 20)      v = W0[col * 400 + k];
      else if (col < 70) v = W1[(col - 20) * 400 + k];
    }
  }
  out[idx] = f2bf(v);
}

__global__ void build_bias3(const float* a, const float* b, const float* c, float* o) {
  int i = blockIdx.x * 256 + threadIdx.x;
  if (i < 416) o[i] = (i < 400) ? (a[i] + b[i] + c[i]) : 0.f;
}
__global__ void build_bhead(const float* blin, const float* bd1, float* o) {
  int i = threadIdx.x;
  if (i < 512) o[i] = (i < 20) ? blin[i] : ((i < 70) ? bd1[i - 20] : 0.f);
}

// ---------------- MFMA GEMM: 128x512 block, 512 thr (8 waves 2Mx4N), BK=32 ----------------
// AMODE 0: A f32 (cvt->bf16 in staging, k-guarded by Kreal); AMODE 1: A bf16 stride-416.
// OMODE 0: C bf16 [M][416], cols<Nreal get acc+bias, cols Nreal..415 get 0.
// OMODE 1: head split f32: col<20 -> Cv[row*20+col], 20<=col<70 -> C2[row*50+col-20].
template<int AMODE, int OMODE>
__global__ __launch_bounds__(512, 1) void gemm512(
    const void* __restrict__ Av, const unsigned short* __restrict__ Bf,
    const float* __restrict__ bias, void* __restrict__ Cv, float* __restrict__ C2,
    int M, int Kreal, int Astride, int ksteps, int Nreal)
{
  __shared__ unsigned short As[2][128][40];   // pad-40 rows: frag reads spread over banks
  __shared__ unsigned short Bs[2][16384];     // fragment-order, linear
  const int tid = threadIdx.x;
  const int lane = tid & 63;
  const int wv = tid >> 6;
  const int wr = wv >> 2, wc = wv & 3;
  const int rowBase = blockIdx.x * 128;
  const int sRow = tid >> 2;                  // 0..127
  const int sSlot = (tid & 3) << 3;           // 0,8,16,24 (elements)
  const int aRow = rowBase + sRow;
  const bool aOK = aRow < M;
  const int fr = lane & 15;
  const int fq = lane >> 4;

  const float* Af = (const float*)Av;
  const unsigned short* Ah = (const unsigned short*)Av;

  f32x4 acc[4][8] = {};
  float aRegF[8];
  ushort8 aRegH;
  ushort8 bReg[4];

  auto loadA = [&](int t) {
    const int k0 = t * 32 + sSlot;
    if (AMODE == 0) {
      if (aOK && (k0 + 4) <= Kreal) {
        f32x4 v = *(const f32x4*)(Af + (size_t)aRow * Astride + k0);
        aRegF[0] = v[0]; aRegF[1] = v[1]; aRegF[2] = v[2]; aRegF[3] = v[3];
      } else { aRegF[0] = 0.f; aRegF[1] = 0.f; aRegF[2] = 0.f; aRegF[3] = 0.f; }
      if (aOK && (k0 + 8) <= Kreal) {
        f32x4 v = *(const f32x4*)(Af + (size_t)aRow * Astride + k0 + 4);
        aRegF[4] = v[0]; aRegF[5] = v[1]; aRegF[6] = v[2]; aRegF[7] = v[3];
      } else { aRegF[4] = 0.f; aRegF[5] = 0.f; aRegF[6] = 0.f; aRegF[7] = 0.f; }
    } else {
      if (aOK) aRegH = *(const ushort8*)(Ah + (size_t)aRow * Astride + k0);
      else {
        #pragma unroll
        for (int j = 0; j < 8; ++j) aRegH[j] = 0;
      }
    }
  };
  auto loadB = [&](int t) {
    const unsigned short* bp = Bf + (size_t)t * 16384 + tid * 8;
    #pragma unroll
    for (int i = 0; i < 4; ++i) bReg[i] = *(const ushort8*)(bp + i * 4096);
  };
  auto writeA = [&](int buf) {
    ushort8 w;
    if (AMODE == 0) {
      #pragma unroll
      for (int j = 0; j < 8; ++j) w[j] = f2bf(aRegF[j]);
    } else w = aRegH;
    *(ushort8*)&As[buf][sRow][sSlot] = w;
  };
  auto writeB = [&](int buf) {
    #pragma unroll
    for (int i = 0; i < 4; ++i) *(ushort8*)&Bs[buf][tid * 8 + i * 4096] = bReg[i];
  };
  auto compute = [&](int buf) {
    bf16x8 af[4];
    #pragma unroll
    for (int mi = 0; mi < 4; ++mi)
      af[mi] = *(const bf16x8*)&As[buf][(wr << 6) + (mi << 4) + fr][fq << 3];
    #pragma unroll
    for (int ni = 0; ni < 8; ++ni) {
      bf16x8 bv = *(const bf16x8*)&Bs[buf][(((wc * 8 + ni) * 64) + lane) * 8];
      #pragma unroll
      for (int mi = 0; mi < 4; ++mi)
        acc[mi][ni] = __builtin_amdgcn_mfma_f32_16x16x32_bf16(af[mi], bv, acc[mi][ni], 0, 0, 0);
    }
  };

  loadA(0); loadB(0);
  writeA(0); writeB(0);
  __syncthreads();
  for (int t = 0; t < ksteps; ++t) {
    const int cur = t & 1;
    const bool more = (t + 1) < ksteps;
    if (more) { loadA(t + 1); loadB(t + 1); }
    compute(cur);
    if (more) { writeA(cur ^ 1); writeB(cur ^ 1); }
    __syncthreads();
  }

  // epilogue: C/D layout col=lane&15, row=(lane>>4)*4+r [m89]
  #pragma unroll
  for (int mi = 0; mi < 4; ++mi) {
    const int row0 = rowBase + (wr << 6) + (mi << 4) + (fq << 2);
    #pragma unroll
    for (int ni = 0; ni < 8; ++ni) {
      const int col = wc * 128 + ni * 16 + fr;
      if (OMODE == 0) {
        if (col < 416) {
          unsigned short* C = (unsigned short*)Cv;
          const float bv = (col < Nreal) ? bias[col] : 0.f;
          #pragma unroll
          for (int r = 0; r < 4; ++r) {
            const int row = row0 + r;
            if (row < M) C[(size_t)row * 416 + col] =
                (col < Nreal) ? f2bf(acc[mi][ni][r] + bv) : (unsigned short)0;
          }
        }
      } else {
        if (col < 70) {
          const float bv = bias[col];
          #pragma unroll
          for (int r = 0; r < 4; ++r) {
            const int row = row0 + r;
            if (row < M) {
              float v = acc[mi][ni][r] + bv;
              if (col < 20) ((float*)Cv)[(size_t)row * 20 + col] = v;
              else          C2[(size_t)row * 50 + (col - 20)] = v;
            }
          }
        }
      }
    }
  }
}

// ---------------- CSR build ----------------
__global__ void count_deg(const int* __restrict__ dst, int* __restrict__ cnt, int E) {
  int e = blockIdx.x * 256 + threadIdx.x;
  if (e < E) atomicAdd(&cnt[dst[e]], 1);
}

__global__ void scan_indptr(const int* __restrict__ cnt, int* __restrict__ indptr, int n) {
  __shared__ int sh[1024];
  __shared__ int carrySh;
  const int t = threadIdx.x;
  if (t == 0) carrySh = 0;
  __syncthreads();
  for (int base = 0; base < n; base += 8192) {
    int v[8]; int tsum = 0;
    #pragma unroll
    for (int i = 0; i < 8; ++i) {
      int idx = base + t * 8 + i;
      v[i] = (idx < n) ? cnt[idx] : 0;
      tsum += v[i];
    }
    sh[t] = tsum; __syncthreads();
    for (int off = 1; off < 1024; off <<= 1) {
      int add = (t >= off) ? sh[t - off] : 0;
      __syncthreads();
      sh[t] += add;
      __syncthreads();
    }
    int excl = carrySh + sh[t] - tsum;
    #pragma unroll
    for (int i = 0; i < 8; ++i) {
      int idx = base + t * 8 + i;
      if (idx < n) indptr[idx] = excl;
      excl += v[i];
    }
    __syncthreads();
    if (t == 1023) carrySh += sh[1023];
    __syncthreads();
  }
  if (t == 0) indptr[n] = carrySh;
}

__global__ void fill_csr(const int* __restrict__ src, const int* __restrict__ dst,
                         const int* __restrict__ eid, const float* __restrict__ wall,
                         const int* __restrict__ indptr, int* __restrict__ fillc,
                         int* __restrict__ esrc, float* __restrict__ ew, int E)
{
  int e = blockIdx.x * 256 + threadIdx.x;
  if (e >= E) return;
  int d = dst[e];
  int pos = atomicAdd(&fillc[d], 1);
  int slot = indptr[d] + pos;
  esrc[slot] = src[e];
  ew[slot] = wall[eid[e]];
}

// ---------------- segment mean-aggregate (bf16 in/out, stride 416) ----------------
__global__ __launch_bounds__(256) void seg_mean_bf(
    const unsigned short* __restrict__ h, const int* __restrict__ indptr,
    const int* __restrict__ esrc, const float* __restrict__ ew,
    unsigned short* __restrict__ out, int nDst)
{
  const int node = blockIdx.x * 4 + (threadIdx.x >> 6);
  if (node >= nDst) return;
  const int lane = threadIdx.x & 63;
  const bool act = lane < 52;                 // 52*8 = 416 dims
  float a[8];
  if (act) {
    ushort8 v = *(const ushort8*)(h + (size_t)node * 416 + lane * 8);
    #pragma unroll
    for (int j = 0; j < 8; ++j) a[j] = bf2f(v[j]);
  } else {
    #pragma unroll
    for (int j = 0; j < 8; ++j) a[j] = 0.f;
  }
  const int e0 = indptr[node], e1 = indptr[node + 1];
  for (int e = e0; e < e1; ++e) {
    const int s = esrc[e];
    const float w = ew[e];
    if (act) {
      ushort8 v = *(const ushort8*)(h + (size_t)s * 416 + lane * 8);
      #pragma unroll
      for (int j = 0; j < 8; ++j) a[j] += bf2f(v[j]) * w;
    }
  }
  const float inv = 1.f / ((float)(e1 - e0) + 1.f);
  if (act) {
    ushort8 o;
    #pragma unroll
    for (int j = 0; j < 8; ++j) o[j] = f2bf(a[j] * inv);
    *(ushort8*)(out + (size_t)node * 416 + lane * 8) = o;
  }
}

// ---------------- batchnorm + domain head ----------------
__global__ void bn_stats(const float* __restrict__ d, float* __restrict__ stats, int rows) {
  int lane = threadIdx.x & 63;
  int wid = (blockIdx.x * blockDim.x + threadIdx.x) >> 6;
  int nw = (gridDim.x * blockDim.x) >> 6;
  if (lane >= 50) return;
  float s = 0.f, s2 = 0.f;
  for (int r = wid; r < rows; r += nw) {
    float v = d[r * 50 + lane];
    s += v; s2 += v * v;
  }
  atomicAdd(&stats[lane], s);
  atomicAdd(&stats[50 + lane], s2);
}

__global__ void bn_final(const float* __restrict__ stats, const float* __restrict__ gamma,
                         const float* __restrict__ beta, float* __restrict__ ss, int rows) {
  int c = threadIdx.x;
  if (c >= 50) return;
  float mu = stats[c] / rows;
  float var = stats[50 + c] / rows - mu * mu;
  float inv = rsqrtf(var + 1e-5f);
  float sc = gamma[c] * inv;
  ss[c] = sc;
  ss[50 + c] = beta[c] - mu * sc;
}

__global__ void domain_head(const float* __restrict__ d, const float* __restrict__ ss,
                            const float* __restrict__ Wd2, const float* __restrict__ bd2,
                            float* __restrict__ out, int rows) {
  int r = blockIdx.x * 256 + threadIdx.x;
  if (r >= rows) return;
  float o0 = bd2[0], o1 = bd2[1];
  const float* dr = d + (size_t)r * 50;
  #pragma unroll 10
  for (int c = 0; c < 50; ++c) {
    float v = dr[c] * ss[c] + ss[50 + c];
    v = fmaxf(v, 0.f);
    o0 += v * Wd2[c];
    o1 += v * Wd2[50 + c];
  }
  out[r * 2]     = o0;
  out[r * 2 + 1] = o1;
}

// ---------------- launch ----------------
extern "C" void kernel_launch(void* const* d_in, const int* in_sizes, int n_in,
                              void* d_out, int out_size, void* d_ws, size_t ws_size,
                              hipStream_t stream)
{
  const float* x    = (const float*)d_in[0];
  const float* wall = (const float*)d_in[1];
  const float* Wsh  = (const float*)d_in[2];
  const float* bsh  = (const float*)d_in[3];
  const float* Whu  = (const float*)d_in[4];
  const float* bhu  = (const float*)d_in[5];
  const float* Wmo  = (const float*)d_in[6];
  const float* bmo  = (const float*)d_in[7];
  const float* Wn1  = (const float*)d_in[8];
  const float* bn1  = (const float*)d_in[9];
  const float* Wn2  = (const float*)d_in[10];
  const float* bn2  = (const float*)d_in[11];
  const float* Wlin = (const float*)d_in[12];
  const float* blin = (const float*)d_in[13];
  const float* Wd1  = (const float*)d_in[14];
  const float* bd1  = (const float*)d_in[15];
  const float* gamma= (const float*)d_in[16];
  const float* beta = (const float*)d_in[17];
  const float* Wd2  = (const float*)d_in[18];
  const float* bd2  = (const float*)d_in[19];
  const int* src1 = (const int*)d_in[20];
  const int* dst1 = (const int*)d_in[21];
  const int* eid1 = (const int*)d_in[22];
  const int* src2 = (const int*)d_in[23];
  const int* dst2 = (const int*)d_in[24];
  const int* eid2 = (const int*)d_in[25];

  char* ws = (char*)d_ws;
  unsigned short* h    = (unsigned short*)(ws);                    // [60000][416] bf16
  unsigned short* hn1  = (unsigned short*)(ws + 49920000ULL);      // [30000][416]
  unsigned short* h1   = (unsigned short*)(ws + 74880000ULL);      // [30000][416]
  unsigned short* hn2  = (unsigned short*)(ws + 99840000ULL);      // [15000][416]
  unsigned short* h2   = (unsigned short*)(ws + 112320000ULL);     // [15000][416]
  float* d_raw         = (float*)(ws + 124800000ULL);              // [15000][50] f32
  unsigned short* WCf  = (unsigned short*)(ws + 127800000ULL);     // 63*16384
  unsigned short* WN1f = (unsigned short*)(ws + 129864384ULL);     // 13*16384
  unsigned short* WN2f = (unsigned short*)(ws + 130290368ULL);
  unsigned short* WHf  = (unsigned short*)(ws + 130716352ULL);
  float* b3      = (float*)(ws + 131142336ULL);
  float* bhead   = (float*)(ws + 131144384ULL);
  int*   cnt1    = (int*)(ws + 131146432ULL);
  int*   indptr1 = (int*)(ws + 131266496ULL);
  int*   fill1   = (int*)(ws + 131386560ULL);
  int*   esrc1   = (int*)(ws + 131506624ULL);
  float* ew1     = (float*)(ws + 135346624ULL);
  int*   cnt2    = (int*)(ws + 139186624ULL);
  int*   indptr2 = (int*)(ws + 139246688ULL);
  int*   fill2   = (int*)(ws + 139306752ULL);
  int*   esrc2   = (int*)(ws + 139366816ULL);
  float* ew2     = (float*)(ws + 141286816ULL);
  float* stats   = (float*)(ws + 143206816ULL);
  float* ssb     = (float*)(ws + 143207328ULL);

  const int E1 = 960000, E2 = 480000;
  const int N0 = 60000, N1 = 30000, N2 = 15000;

  // weight prep (fragment-order B) + biases
  build_bfrag<<<(63 * 16384 + 255) / 256, 256, 0, stream>>>(Wsh, Whu, Wmo, WCf, 63, 0, 400, 2000);
  build_bfrag<<<(13 * 16384 + 255) / 256, 256, 0, stream>>>(Wn1, nullptr, nullptr, WN1f, 13, 1, 400, 400);
  build_bfrag<<<(13 * 16384 + 255) / 256, 256, 0, stream>>>(Wn2, nullptr, nullptr, WN2f, 13, 1, 400, 400);
  build_bfrag<<<(13 * 16384 + 255) / 256, 256, 0, stream>>>(Wlin, Wd1, nullptr, WHf, 13, 2, 70, 400);
  build_bias3<<<2, 256, 0, stream>>>(bsh, bhu, bmo, b3);
  build_bhead<<<1, 512, 0, stream>>>(blin, bd1, bhead);

  hipMemsetAsync(cnt1, 0, 120000, stream);
  hipMemsetAsync(fill1, 0, 120000, stream);
  hipMemsetAsync(cnt2, 0, 60000, stream);
  hipMemsetAsync(fill2, 0, 60000, stream);
  hipMemsetAsync(stats, 0, 400, stream);

  // stage 1: h = bf16(x @ Wcat.T + b3)  [60000][416]
  gemm512<0, 0><<<469, 512, 0, stream>>>(x, WCf, b3, h, nullptr, N0, 2000, 2000, 63, 400);

  // GNN layer 1
  count_deg<<<(E1 + 255) / 256, 256, 0, stream>>>(dst1, cnt1, E1);
  scan_indptr<<<1, 1024, 0, stream>>>(cnt1, indptr1, N1);
  fill_csr<<<(E1 + 255) / 256, 256, 0, stream>>>(src1, dst1, eid1, wall, indptr1, fill1, esrc1, ew1, E1);
  seg_mean_bf<<<N1 / 4, 256, 0, stream>>>(h, indptr1, esrc1, ew1, hn1, N1);
  gemm512<1, 0><<<235, 512, 0, stream>>>(hn1, WN1f, bn1, h1, nullptr, N1, 416, 416, 13, 400);

  // GNN layer 2
  count_deg<<<(E2 + 255) / 256, 256, 0, stream>>>(dst2, cnt2, E2);
  scan_indptr<<<1, 1024, 0, stream>>>(cnt2, indptr2, N2);
  fill_csr<<<(E2 + 255) / 256, 256, 0, stream>>>(src2, dst2, eid2, wall, indptr2, fill2, esrc2, ew2, E2);
  seg_mean_bf<<<N2 / 4, 256, 0, stream>>>(h1, indptr2, esrc2, ew2, hn2, N2);
  gemm512<1, 0><<<118, 512, 0, stream>>>(hn2, WN2f, bn2, h2, nullptr, N2, 416, 416, 13, 400);

  // fused heads: cols 0..19 -> h_x (d_out), 20..69 -> d_raw
  float* out_hx  = (float*)d_out;            // 15000 x 20
  float* out_dom = (float*)d_out + 300000;   // 15000 x 2
  gemm512<1, 1><<<118, 512, 0, stream>>>(h2, WHf, bhead, out_hx, d_raw, N2, 416, 416, 13, 70);

  bn_stats<<<128, 256, 0, stream>>>(d_raw, stats, N2);
  bn_final<<<1, 64, 0, stream>>>(stats, gamma, beta, ssb, N2);
  domain_head<<<(N2 + 255) / 256, 256, 0, stream>>>(d_raw, ssb, Wd2, bd2, out_dom, N2);
}